// Round 5
// baseline (2285.780 us; speedup 1.0000x reference)
//
#include <hip/hip_runtime.h>
#include <math.h>

typedef unsigned short u16;
typedef __bf16 bf16x8 __attribute__((ext_vector_type(8)));
typedef unsigned short u16x8 __attribute__((ext_vector_type(8)));
typedef float f32x4 __attribute__((ext_vector_type(4)));

#define HWQ 16384
#define PI_F 3.14159265358979323846f

// canonical (bf16) input offsets inside ws
#define C_X     0
#define C_TOK   262144
#define C_QW    1310720
#define C_QB    1376256
#define C_WQ    1376768
#define C_WKV   1442304
#define C_WO    1704448
#define C_BO    1769984
#define C_BWW   1770496
#define C_BWB   1967104
#define C_MODW  1968640
#define C_MODB  2755072
#define C_HVW   2756608
#define C_HVB   3280896
#define C_OUTW  3281920
#define C_OUTB  3286528
#define C_TOTAL 3286537
#define CANON_PAD 3286544   // canon region size (u16), 16B-aligned end

// WT (transposed weights) element offsets (relative to WT base)
#define QWT_OFF  0         // q_W^T   [512][128]
#define WQT_OFF  65536     // Wq^T    [128][512]
#define WOT_OFF  131072    // Wo^T    [512][128]
#define BWT_OFF  196608    // bw_W^T  3x[512][128]
#define MODT_OFF 393216    // mod_W^T 3x[512][512]
#define HVT_OFF  1179648   // hv_W^T  2x[512][512]

struct SrcPtrs { const void* p[16]; };

__device__ __forceinline__ float bs2f(u16 u){
  unsigned v = ((unsigned)u) << 16; float f; __builtin_memcpy(&f, &v, 4); return f;
}
__device__ __forceinline__ u16 f2bs(float f){
  unsigned v; __builtin_memcpy(&v, &f, 4);
  v = (v + 0x7fffu + ((v >> 16) & 1u)) >> 16;
  return (u16)v;
}
__device__ __forceinline__ f32x4 mfma16(bf16x8 a, bf16x8 b, f32x4 c){
  return __builtin_amdgcn_mfma_f32_16x16x32_bf16(a, b, c, 0, 0, 0);
}
__device__ __forceinline__ bf16x8 ld8(const u16* p){ return *(const bf16x8*)p; }

// ---------------- dtype detect: q_b even u16 indices ----------------
__global__ void k_detect(const u16* qb_raw, unsigned* flag){
  __shared__ int cnt[256];
  int t = threadIdx.x;
  u16 u = qb_raw[2*t];
  int e = (u >> 7) & 0xFF;
  cnt[t] = (e >= 126) ? 1 : 0;
  __syncthreads();
  for (int s = 128; s > 0; s >>= 1){
    if (t < s) cnt[t] += cnt[t + s];
    __syncthreads();
  }
  if (t == 0) *flag = (cnt[0] >= 16) ? 1u : 0u;
}

// ---------------- convert all inputs to canonical bf16 ----------------
__global__ __launch_bounds__(256) void k_convert(SrcPtrs sp, const unsigned* flag, u16* canon){
  const int offs[17] = {C_X,C_TOK,C_QW,C_QB,C_WQ,C_WKV,C_WO,C_BO,C_BWW,C_BWB,
                        C_MODW,C_MODB,C_HVW,C_HVB,C_OUTW,C_OUTB,C_TOTAL};
  int e = blockIdx.x * 256 + threadIdx.x;
  if (e >= C_TOTAL) return;
  int seg = 0;
  for (int i = 1; i < 16; i++) if (e >= offs[i]) seg = i;
  int local = e - offs[seg];
  if (*flag){
    canon[e] = f2bs(((const float*)sp.p[seg])[local]);
  } else {
    canon[e] = ((const u16*)sp.p[seg])[local];
  }
}

// ---------------- weight transpose: dst[n][k] = src[k][n] ----------------
__global__ __launch_bounds__(256) void k_tr(const u16* canon, u16* WT){
  __shared__ u16 tile[32][33];
  int bid = blockIdx.x, t = threadIdx.x;
  const u16* src; u16* dst; int K, N, tl;
  if (bid < 384){
    int m = bid >> 6; tl = bid & 63;
    if (m == 0){ src = canon + C_QW;  dst = WT + QWT_OFF; K = 128; N = 512; }
    else if (m == 1){ src = canon + C_WQ; dst = WT + WQT_OFF; K = 512; N = 128; }
    else if (m == 2){ src = canon + C_WO; dst = WT + WOT_OFF; K = 128; N = 512; }
    else { src = canon + C_BWW + (m-3)*65536; dst = WT + BWT_OFF + (m-3)*65536; K = 128; N = 512; }
  } else if (bid < 1152){
    int m = (bid - 384) >> 8; tl = (bid - 384) & 255;
    src = canon + C_MODW + m*262144; dst = WT + MODT_OFF + m*262144; K = 512; N = 512;
  } else {
    int m = (bid - 1152) >> 8; tl = (bid - 1152) & 255;
    src = canon + C_HVW + m*262144; dst = WT + HVT_OFF + m*262144; K = 512; N = 512;
  }
  int kt = K >> 5;
  int k0 = (tl % kt) * 32, n0 = (tl / kt) * 32;
  int tx = t & 31, ty = t >> 5;
  for (int r = 0; r < 4; r++)
    tile[ty + r*8][tx] = src[(size_t)(k0 + ty + r*8) * N + n0 + tx];
  __syncthreads();
  for (int r = 0; r < 4; r++)
    dst[(size_t)(n0 + ty + r*8) * K + k0 + tx] = tile[tx][ty + r*8];
}

// ---------------- kv = tokens @ Wkv ; k->[b][kk][d], v->[b][d][kk] ----------------
__global__ __launch_bounds__(256) void k_kv(const u16* canon, u16* kpart, u16* vT){
  int b = blockIdx.x >> 8, kk = blockIdx.x & 255, t = threadIdx.x;
  const u16* tok = canon + C_TOK;
  const u16* Wkv = canon + C_WKV;
  __shared__ float tk[512];
  const u16* tr = tok + ((size_t)(b*256 + kk)) * 512;
  tk[t] = bs2f(tr[t]); tk[t+256] = bs2f(tr[t+256]);
  __syncthreads();
  float acc = 0.f;
  for (int k = 0; k < 512; k++) acc += tk[k] * bs2f(Wkv[k*256 + t]);
  if (t < 128) kpart[((size_t)(b*256 + kk))*128 + t] = f2bs(acc);
  else vT[((size_t)b*128 + (t-128))*256 + kk] = f2bs(acc);
}

// ---------------- per-query: gamma -> xq -> qvec ; h_l bands ----------------
__global__ __launch_bounds__(256) void k_query(const u16* canon, const float* xraw,
      const unsigned* flag, const u16* WT, u16* qvecB, u16* hlB){
  int t = threadIdx.x, q0 = blockIdx.x * 16;
  const u16* q_b = canon + C_QB;
  const u16* bw_b= canon + C_BWB;
  int lane = t & 63, wv = t >> 6, l15 = lane & 15, q4 = lane >> 4;
  __shared__ __align__(16) u16 g[16*136];
  __shared__ __align__(16) u16 xql[16*520];
  __shared__ float cco[32];
  __shared__ float omg[32];
  for (int e = t; e < 16*136; e += 256) g[e] = 0;
  for (int e = t; e < 16*520; e += 256) xql[e] = 0;
  if (t < 32) cco[t] = (*flag) ? xraw[q0*2 + t] : bs2f(canon[C_X + q0*2 + t]);
  if (t < 32) omg[t] = (float)pow(10.0, 1.0 + t * ((2.1072099696478683 - 1.0)/31.0));
  __syncthreads();
  for (int i = 0; i < 8; i++){
    int id = i*256 + t, qi = id >> 7, f = id & 127;
    int d = f >> 6, r = f & 63, fi = r & 31;
    float arg = PI_F * cco[qi*2 + d] * omg[fi];
    g[qi*136 + f] = f2bs((r < 32) ? sinf(arg) : cosf(arg));
  }
  __syncthreads();
  { // xq = relu(g @ q_W + q_b)  -> xql (LDS)
    const u16* Bm = WT + QWT_OFF;
    for (int nt = 0; nt < 8; nt++){
      f32x4 acc = {0.f,0.f,0.f,0.f};
      int c = wv*128 + nt*16 + l15;
      for (int ks = 0; ks < 4; ks++){
        bf16x8 a  = ld8(g + l15*136 + ks*32 + q4*8);
        bf16x8 bb = ld8(Bm + (size_t)c*128 + ks*32 + q4*8);
        acc = mfma16(a, bb, acc);
      }
      float qb = bs2f(q_b[c]);
      for (int rg = 0; rg < 4; rg++){
        int row = q4*4 + rg;
        xql[row*520 + c] = f2bs(fmaxf(acc[rg] + qb, 0.f));
      }
    }
  }
  __syncthreads();
  { // qvec = xq @ Wq
    const u16* Bm = WT + WQT_OFF;
    for (int nh = 0; nh < 2; nh++){
      f32x4 acc = {0.f,0.f,0.f,0.f};
      int c = wv*32 + nh*16 + l15;
      for (int ks = 0; ks < 16; ks++){
        bf16x8 a  = ld8(xql + l15*520 + ks*32 + q4*8);
        bf16x8 bb = ld8(Bm + (size_t)c*512 + ks*32 + q4*8);
        acc = mfma16(a, bb, acc);
      }
      for (int rg = 0; rg < 4; rg++){
        int row = q4*4 + rg;
        qvecB[(size_t)(q0 + row)*128 + c] = f2bs(acc[rg]);
      }
    }
  }
  const double LG[3] = {1.2041199826559248, 1.8061799739838869, 2.4082399653118496};
  for (int ib = 0; ib < 3; ib++){
    __syncthreads();
    if (t < 32) omg[t] = (float)pow(10.0, 1.0 + t * ((LG[ib] - 1.0)/31.0));
    __syncthreads();
    for (int i = 0; i < 8; i++){
      int id = i*256 + t, qi = id >> 7, f = id & 127;
      int d = f >> 6, r = f & 63, fi = r & 31;
      float arg = PI_F * cco[qi*2 + d] * omg[fi];
      g[qi*136 + f] = f2bs((r < 32) ? sinf(arg) : cosf(arg));
    }
    __syncthreads();
    const u16* Bm = WT + BWT_OFF + ib*65536;
    for (int nt = 0; nt < 8; nt++){
      f32x4 acc = {0.f,0.f,0.f,0.f};
      int c = wv*128 + nt*16 + l15;
      for (int ks = 0; ks < 4; ks++){
        bf16x8 a  = ld8(g + l15*136 + ks*32 + q4*8);
        bf16x8 bb = ld8(Bm + (size_t)c*128 + ks*32 + q4*8);
        acc = mfma16(a, bb, acc);
      }
      float bias = bs2f(bw_b[ib*512 + c]);
      for (int rg = 0; rg < 4; rg++){
        int row = q4*4 + rg;
        hlB[((size_t)ib*HWQ + q0 + row)*512 + c] = f2bs(fmaxf(acc[rg] + bias, 0.f));
      }
    }
  }
}

// ---------------- attention + mod projection (f32 softmax) ----------------
__global__ __launch_bounds__(256) void k_attn(const u16* canon, const float* xraw,
      const unsigned* flag, const u16* qvecB, const u16* kpart, const u16* vT,
      const u16* WT, u16* modB){
  int t = threadIdx.x;
  int b = blockIdx.x & 7, qt = blockIdx.x >> 3, q0 = qt*32;
  const u16* bo = canon + C_BO;
  int lane = t & 63, wv = t >> 6, l15 = lane & 15, q4 = lane >> 4;
  __shared__ __align__(16) u16 ql[32*136];
  __shared__ __align__(16) u16 pl[32*264];
  __shared__ float pf[32*264];
  __shared__ __align__(16) u16 ot[32*136];
  __shared__ float tqs[32];
  __shared__ float red[256];
  __shared__ float rst[32];
  for (int e = t; e < 32*136; e += 256){ ql[e] = 0; ot[e] = 0; }
  for (int e = t; e < 32*264; e += 256) pl[e] = 0;
  __syncthreads();
  for (int i = 0; i < 16; i++){
    int id = i*256 + t, qi = id >> 7, c = id & 127;
    ql[qi*136 + c] = qvecB[(size_t)(q0 + qi)*128 + c];
  }
  if (t < 32){
    float c0, c1;
    if (*flag){ c0 = xraw[(q0+t)*2]; c1 = xraw[(q0+t)*2 + 1]; }
    else { c0 = bs2f(canon[C_X + (q0+t)*2]); c1 = bs2f(canon[C_X + (q0+t)*2 + 1]); }
    int rr = (int)(c0*16.f), cc = (int)(c1*16.f);
    tqs[t] = (float)(rr*16 + cc) * (1.f/256.f);
  }
  __syncthreads();
  for (int h = 0; h < 2; h++){
    f32x4 sac[2][4];
    for (int mt = 0; mt < 2; mt++) for (int nt = 0; nt < 4; nt++) sac[mt][nt] = (f32x4){0.f,0.f,0.f,0.f};
    const u16* kb = kpart + (size_t)b*256*128 + h*64;
    for (int ks = 0; ks < 2; ks++){
      bf16x8 a0 = ld8(ql + l15*136 + h*64 + ks*32 + q4*8);
      bf16x8 a1 = ld8(ql + (16+l15)*136 + h*64 + ks*32 + q4*8);
      for (int nt = 0; nt < 4; nt++){
        int kk = wv*64 + nt*16 + l15;
        bf16x8 bb = ld8(kb + (size_t)kk*128 + ks*32 + q4*8);
        sac[0][nt] = mfma16(a0, bb, sac[0][nt]);
        sac[1][nt] = mfma16(a1, bb, sac[1][nt]);
      }
    }
    for (int mt = 0; mt < 2; mt++) for (int nt = 0; nt < 4; nt++){
      int kk = wv*64 + nt*16 + l15;
      float pos = ((float)kk + 0.5f) * (1.f/256.f);
      for (int rg = 0; rg < 4; rg++){
        int row = mt*16 + q4*4 + rg;
        float dd = tqs[row] - pos;
        pf[row*264 + kk] = sac[mt][nt][rg]*0.125f - 10.f*dd*dd;
      }
    }
    __syncthreads();
    { // f32 softmax over 256 keys per row; bf16 P out
      int r = t >> 3, i = t & 7;
      float* pr = pf + r*264 + i*32;
      u16* po = pl + r*264 + i*32;
      float m = -1e30f;
      for (int j = 0; j < 32; j++) m = fmaxf(m, pr[j]);
      red[t] = m;
      __syncthreads();
      if (t < 32){ float mm = red[t*8];
        for (int j = 1; j < 8; j++) mm = fmaxf(mm, red[t*8+j]);
        rst[t] = mm; }
      __syncthreads();
      float mm = rst[r], sum = 0.f;
      for (int j = 0; j < 32; j++){ float e = expf(pr[j] - mm); pr[j] = e; sum += e; }
      red[t] = sum;
      __syncthreads();
      if (t < 32){ float ss = 0.f;
        for (int j = 0; j < 8; j++) ss += red[t*8+j];
        rst[t] = 1.f/ss; }
      __syncthreads();
      float inv = rst[r];
      for (int j = 0; j < 32; j++) po[j] = f2bs(pr[j] * inv);
    }
    __syncthreads();
    f32x4 oac[2] = {(f32x4){0.f,0.f,0.f,0.f}, (f32x4){0.f,0.f,0.f,0.f}};
    const u16* vb = vT + ((size_t)b*128 + h*64)*256;
    int dl = wv*16 + l15;
    for (int ks = 0; ks < 8; ks++){
      bf16x8 a0 = ld8(pl + l15*264 + ks*32 + q4*8);
      bf16x8 a1 = ld8(pl + (16+l15)*264 + ks*32 + q4*8);
      bf16x8 bb = ld8(vb + (size_t)dl*256 + ks*32 + q4*8);
      oac[0] = mfma16(a0, bb, oac[0]);
      oac[1] = mfma16(a1, bb, oac[1]);
    }
    for (int mt = 0; mt < 2; mt++) for (int rg = 0; rg < 4; rg++){
      int row = mt*16 + q4*4 + rg;
      ot[row*136 + h*64 + dl] = f2bs(oac[mt][rg]);
    }
    __syncthreads();
  }
  const u16* wob = WT + WOT_OFF;
  for (int nt = 0; nt < 8; nt++){
    f32x4 mac[2] = {(f32x4){0.f,0.f,0.f,0.f}, (f32x4){0.f,0.f,0.f,0.f}};
    int c = wv*128 + nt*16 + l15;
    for (int ks = 0; ks < 4; ks++){
      bf16x8 a0 = ld8(ot + l15*136 + ks*32 + q4*8);
      bf16x8 a1 = ld8(ot + (16+l15)*136 + ks*32 + q4*8);
      bf16x8 bb = ld8(wob + (size_t)c*128 + ks*32 + q4*8);
      mac[0] = mfma16(a0, bb, mac[0]);
      mac[1] = mfma16(a1, bb, mac[1]);
    }
    float bv = bs2f(bo[c]);
    for (int mt = 0; mt < 2; mt++) for (int rg = 0; rg < 4; rg++){
      int row = mt*16 + q4*4 + rg;
      modB[((size_t)(q0+row)*8 + b)*512 + c] = f2bs(mac[mt][rg] + bv);
    }
  }
}

// ---------------- fused band/chain GEMMs (simple staging) ----------------
__device__ __forceinline__ void do_gemm(
    int aglob, const u16* Ag, const u16* Al,
    const u16* Bm, u16* bsl,
    int mode, const u16* biasv, const u16* hlrow,
    u16* Xw, const u16* Xr, int t)
{
  int lane = t & 63, wv = t >> 6, wm = wv >> 1, wn = wv & 1;
  int l15 = lane & 15, q4 = lane >> 4;
  for (int nb = 0; nb < 4; nb++){
    f32x4 acc[2][4];
    for (int mt = 0; mt < 2; mt++) for (int nt = 0; nt < 4; nt++) acc[mt][nt] = (f32x4){0.f,0.f,0.f,0.f};
    for (int ks = 0; ks < 16; ks++){
      __syncthreads();
      {
        int c0 = t, c1 = t + 256;
        u16x8 v0 = *(const u16x8*)(Bm + (size_t)(nb*128 + (c0>>2))*512 + ks*32 + (c0&3)*8);
        u16x8 v1 = *(const u16x8*)(Bm + (size_t)(nb*128 + (c1>>2))*512 + ks*32 + (c1&3)*8);
        *(u16x8*)(bsl + (c0>>2)*40 + (c0&3)*8) = v0;
        *(u16x8*)(bsl + (c1>>2)*40 + (c1&3)*8) = v1;
      }
      __syncthreads();
      bf16x8 a0, a1;
      if (aglob){
        a0 = ld8(Ag + (size_t)(wm*32 + l15)*512 + ks*32 + q4*8);
        a1 = ld8(Ag + (size_t)(wm*32 + 16 + l15)*512 + ks*32 + q4*8);
      } else {
        a0 = ld8(Al + (wm*32 + l15)*520 + ks*32 + q4*8);
        a1 = ld8(Al + (wm*32 + 16 + l15)*520 + ks*32 + q4*8);
      }
      for (int nt = 0; nt < 4; nt++){
        bf16x8 bb = ld8(bsl + (wn*64 + nt*16 + l15)*40 + q4*8);
        acc[0][nt] = mfma16(a0, bb, acc[0][nt]);
        acc[1][nt] = mfma16(a1, bb, acc[1][nt]);
      }
    }
    __syncthreads();
    for (int mt = 0; mt < 2; mt++) for (int nt = 0; nt < 4; nt++){
      int col = nb*128 + wn*64 + nt*16 + l15;
      float bias = bs2f(biasv[col]);
      for (int rg = 0; rg < 4; rg++){
        int row = wm*32 + mt*16 + q4*4 + rg;
        float v = acc[mt][nt][rg] + bias;
        if (mode <= 1) v += bs2f(hlrow[(size_t)(row >> 3)*512 + col]);
        v = fmaxf(v, 0.f);
        if (mode == 1) v += bs2f(Xr[row*520 + col]);
        Xw[row*520 + col] = f2bs(v);
      }
    }
  }
}

__device__ __forceinline__ void proj(int i, const u16* X, const u16* outW, const u16* outb,
                                     u16* bsl, float* totv, int t){
  float* owf = (float*)bsl;
  for (int e = t; e < 1536; e += 256) owf[e] = bs2f(outW[i*1536 + e]);
  __syncthreads();
  if (t < 192){
    int r = t/3, o = t - (t/3)*3;
    float s = bs2f(outb[i*3 + o]);
    const u16* xr = X + r*520;
    for (int c = 0; c < 512; c++) s += bs2f(xr[c]) * owf[c*3 + o];
    *totv += s;
  }
  __syncthreads();
}

__global__ __launch_bounds__(256) void k_bands(const u16* canon, const u16* modB,
      const u16* WT, const u16* hlB, const unsigned* flag, void* outv){
  int t = threadIdx.x;
  int rgp = blockIdx.x, q0 = rgp*8;
  const u16* mod_b = canon + C_MODB;
  const u16* hv_b  = canon + C_HVB;
  const u16* outW  = canon + C_OUTW;
  const u16* outb  = canon + C_OUTB;
  __shared__ __align__(16) u16 xa[64*520];
  __shared__ __align__(16) u16 xb[64*520];
  __shared__ __align__(16) u16 bsl[5120];
  for (int e = t; e < 64*520; e += 256){ xa[e] = 0; xb[e] = 0; }
  for (int e = t; e < 5120; e += 256) bsl[e] = 0;
  __syncthreads();
  const u16* Ag = modB + (size_t)rgp*64*512;
  float totv = 0.f;
  do_gemm(1, Ag, 0, WT + MODT_OFF, bsl, 0, mod_b, hlB + (size_t)q0*512, xa, 0, t);
  __syncthreads();
  proj(0, xa, outW, outb, bsl, &totv, t);
  do_gemm(1, Ag, 0, WT + MODT_OFF + 262144, bsl, 1, mod_b + 512, hlB + (size_t)(HWQ + q0)*512, xb, xa, t);
  __syncthreads();
  do_gemm(0, 0, xb, WT + HVT_OFF, bsl, 2, hv_b, 0, xa, 0, t);
  __syncthreads();
  proj(1, xa, outW, outb, bsl, &totv, t);
  do_gemm(1, Ag, 0, WT + MODT_OFF + 524288, bsl, 1, mod_b + 1024, hlB + (size_t)(2*HWQ + q0)*512, xb, xa, t);
  __syncthreads();
  do_gemm(0, 0, xb, WT + HVT_OFF + 262144, bsl, 2, hv_b + 512, 0, xa, 0, t);
  __syncthreads();
  proj(2, xa, outW, outb, bsl, &totv, t);
  if (t < 192){
    int r = t/3, o = t - (t/3)*3;
    int bb2 = r & 7, qq = q0 + (r >> 3);
    size_t idx = ((size_t)bb2*HWQ + qq)*3 + o;
    if (*flag) ((float*)outv)[idx] = totv;
    else       ((u16*)outv)[idx]   = f2bs(totv);
  }
}

extern "C" void kernel_launch(void* const* d_in, const int* in_sizes, int n_in,
                              void* d_out, int out_size, void* d_ws, size_t ws_size,
                              hipStream_t stream){
  (void)in_sizes; (void)n_in; (void)out_size;

  u16* wsp   = (u16*)d_ws;
  unsigned* flag = (unsigned*)wsp;     // 8 u16 slot
  u16* canon = wsp + 8;                // CANON_PAD elems
  u16* WT    = canon + CANON_PAD;      // 1,703,936
  u16* kpart = WT + 1703936;           //   262,144
  u16* vT    = kpart + 262144;         //   262,144
  u16* qvecB = vT + 262144;            // 2,097,152
  u16* hlB   = qvecB + 2097152;        // 25,165,824
  u16* modB  = hlB + 25165824;         // 67,108,864
  if (ws_size < 199773250ULL) return;  // (8+CANON_PAD+96,600,064) * 2B

  SrcPtrs sp;
  for (int i = 0; i < 16; i++) sp.p[i] = d_in[i];
  const float* xraw = (const float*)d_in[0];

  k_detect <<<1, 256, 0, stream>>>((const u16*)d_in[3], flag);
  k_convert<<<(C_TOTAL + 255)/256, 256, 0, stream>>>(sp, flag, canon);
  k_tr     <<<1664, 256, 0, stream>>>(canon, WT);
  k_kv     <<<2048, 256, 0, stream>>>(canon, kpart, vT);
  k_query  <<<1024, 256, 0, stream>>>(canon, xraw, flag, WT, qvecB, hlB);
  k_attn   <<<4096, 256, 0, stream>>>(canon, xraw, flag, qvecB, kpart, vT, WT, modB);
  k_bands  <<<2048, 256, 0, stream>>>(canon, modB, WT, hlB, flag, d_out);
}